// Round 3
// baseline (366.122 us; speedup 1.0000x reference)
//
#include <hip/hip_runtime.h>
#include <hip/hip_bf16.h>
#include <stdint.h>

// dist[i,j] = ||s_i||^2 + ||t_j||^2 - 2 s_i . t_j
// prep: one fused kernel: s -> bf16(-2*s), t -> bf16(t) into d_ws + exact f32
// row norms. main: 128x128 bf16 MFMA GEMM, BK=32, DOUBLE-BUFFERED LDS with
// global_load_lds width=16 issued one iteration ahead (load latency hidden
// under compute; barrier vmcnt drain finds loads already landed), XOR chunk
// swizzle (optimal 8-words/bank ds_read_b128), fused epilogue, nt stores.

typedef __attribute__((ext_vector_type(8))) short short8v;   // 8 bf16 (4 VGPRs)
typedef __attribute__((ext_vector_type(4))) float f32x4;     // 4 fp32 acc

static __device__ __forceinline__ unsigned short f32_to_bf16_rne(float f) {
    unsigned int u = __float_as_uint(f);
    unsigned int lsb = (u >> 16) & 1u;
    u += 0x7fffu + lsb;
    return (unsigned short)(u >> 16);
}

static __device__ __forceinline__ void async_load16(const void* g, void* l) {
    __builtin_amdgcn_global_load_lds(
        (const __attribute__((address_space(1))) void*)g,
        (__attribute__((address_space(3))) void*)l,
        16, 0, 0);
}

// One wave per row (D must be 512). Handles both s (rows < N, scale -2) and
// t (rows >= N, scale 1) in a single launch.
__global__ __launch_bounds__(256) void prep_kernel(const float* __restrict__ s,
                                                   const float* __restrict__ t,
                                                   unsigned short* __restrict__ sb,
                                                   unsigned short* __restrict__ tb,
                                                   float* __restrict__ snrm,
                                                   float* __restrict__ tnrm,
                                                   int N) {
    const int tid  = threadIdx.x;
    const int wid  = tid >> 6;
    const int lane = tid & 63;
    const int g    = blockIdx.x * 4 + wid;
    const bool is_s = (g < N);
    const int row  = is_s ? g : g - N;
    const float* xr = (is_s ? s : t) + (size_t)row * 512;
    unsigned short* xb = (is_s ? sb : tb) + (size_t)row * 512;
    float* nrm = is_s ? snrm : tnrm;
    const float scale = is_s ? -2.0f : 1.0f;

    float4 v0 = ((const float4*)xr)[lane * 2 + 0];
    float4 v1 = ((const float4*)xr)[lane * 2 + 1];

    float ss = v0.x * v0.x + v0.y * v0.y + v0.z * v0.z + v0.w * v0.w
             + v1.x * v1.x + v1.y * v1.y + v1.z * v1.z + v1.w * v1.w;
#pragma unroll
    for (int off = 32; off > 0; off >>= 1) ss += __shfl_down(ss, off, 64);
    if (lane == 0) nrm[row] = ss;

    unsigned short u[8];
    float vals[8] = {v0.x, v0.y, v0.z, v0.w, v1.x, v1.y, v1.z, v1.w};
#pragma unroll
    for (int e = 0; e < 8; ++e) u[e] = f32_to_bf16_rne(vals[e] * scale);
    unsigned int w0 = (unsigned)u[0] | ((unsigned)u[1] << 16);
    unsigned int w1 = (unsigned)u[2] | ((unsigned)u[3] << 16);
    unsigned int w2 = (unsigned)u[4] | ((unsigned)u[5] << 16);
    unsigned int w3 = (unsigned)u[6] | ((unsigned)u[7] << 16);
    ((uint4*)xb)[lane] = make_uint4(w0, w1, w2, w3);
}

#define TILE 128
#define BK 32
// LDS: 2 buffers per matrix, 128x32 bf16 = 8 KB each -> 32 KB total.
// Chunk swizzle: LDS slot (row, c) holds global 16B-chunk c ^ (row&3).
// Staging stays lane-contiguous (global_load_lds HW requirement, m104/m108);
// fragment ds_read_b128: per-bank word demand is exactly 8/wave -> optimal.

__global__ __launch_bounds__(256) void dist_mfma(const unsigned short* __restrict__ sb,
                                                 const unsigned short* __restrict__ tb,
                                                 const float* __restrict__ ssq,
                                                 const float* __restrict__ tsq,
                                                 float* __restrict__ out,
                                                 int N, int Q, int D) {
    __shared__ unsigned short lds_a[2][TILE * BK];
    __shared__ unsigned short lds_b[2][TILE * BK];

    const int tid  = threadIdx.x;
    const int wid  = tid >> 6;
    const int lane = tid & 63;
    const int quad = lane >> 4;
    const int r    = lane & 15;

    // block -> (bm,bn) with 8x8 supertile swizzle for L2 locality
    const int bid = blockIdx.x;
    const int nBm = N / TILE, nBn = Q / TILE;
    int bm, bn;
    if ((nBm & 7) == 0 && (nBn & 7) == 0) {
        const int super = bid >> 6, within = bid & 63;
        const int spr = nBn >> 3;
        const int sm = super / spr, sn = super % spr;
        bm = (sm << 3) + (within >> 3);
        bn = (sn << 3) + (within & 7);
    } else {
        bm = bid / nBn;
        bn = bid - bm * nBn;
    }

    const int m_w = (wid & 1) * 64;   // wave's m offset in tile
    const int n_w = (wid >> 1) * 64;  // wave's n offset in tile

    f32x4 acc[4][4];
#pragma unroll
    for (int a = 0; a < 4; ++a)
#pragma unroll
        for (int b = 0; b < 4; ++b) acc[a][b] = (f32x4){0.f, 0.f, 0.f, 0.f};

    // Staging: 512 16B-chunks per matrix per iter; 2 insts/matrix.
    // Inst j, thread tid covers chunk p = j*256+tid -> row p>>2, slot p&2..,
    // global chunk (p&3)^(row&3). Wave LDS base is uniform + lane*16B.
    const unsigned short* gA[2];
    const unsigned short* gB[2];
    int lofs[2];
#pragma unroll
    for (int j = 0; j < 2; ++j) {
        const int p   = j * 256 + tid;
        const int row = p >> 2;
        const int gch = (p & 3) ^ (row & 3);
        gA[j] = sb + (size_t)(bm * TILE + row) * D + gch * 8;
        gB[j] = tb + (size_t)(bn * TILE + row) * D + gch * 8;
        lofs[j] = (j * 256 + wid * 64) * 8;   // element offset of wave base
    }

    const int nIter = D / BK;  // 16

    // prologue: fill buffer 0
#pragma unroll
    for (int j = 0; j < 2; ++j) {
        async_load16(gA[j], lds_a[0] + lofs[j]);
        async_load16(gB[j], lds_b[0] + lofs[j]);
    }
    __syncthreads();   // drains vmcnt -> buf0 ready

    // fragment read offsets (element): row*BK + (quad^(row&3))*8
    int aofs[4], bofs[4];
#pragma unroll
    for (int im = 0; im < 4; ++im) {
        const int row = m_w + im * 16 + r;
        aofs[im] = row * BK + ((quad ^ (row & 3)) * 8);
    }
#pragma unroll
    for (int in = 0; in < 4; ++in) {
        const int row = n_w + in * 16 + r;
        bofs[in] = row * BK + ((quad ^ (row & 3)) * 8);
    }

    for (int k = 0; k < nIter; ++k) {
        const int cur = k & 1, nxt = cur ^ 1;
        if (k + 1 < nIter) {
            const int k1 = (k + 1) * BK;
#pragma unroll
            for (int j = 0; j < 2; ++j) {
                async_load16(gA[j] + k1, lds_a[nxt] + lofs[j]);
                async_load16(gB[j] + k1, lds_b[nxt] + lofs[j]);
            }
        }
        short8v aF[4], bF[4];
#pragma unroll
        for (int im = 0; im < 4; ++im)
            aF[im] = *(const short8v*)(lds_a[cur] + aofs[im]);
#pragma unroll
        for (int in = 0; in < 4; ++in)
            bF[in] = *(const short8v*)(lds_b[cur] + bofs[in]);
#pragma unroll
        for (int im = 0; im < 4; ++im)
#pragma unroll
            for (int in = 0; in < 4; ++in)
                acc[im][in] = __builtin_amdgcn_mfma_f32_16x16x32_bf16(
                    aF[im], bF[in], acc[im][in], 0, 0, 0);
        __syncthreads();  // reads-from-cur done; loads-into-nxt drained (landed during compute)
    }

    // epilogue: C/D layout col = lane&15, row = quad*4 + reg; nt stores keep
    // the L2-resident bf16 inputs from being evicted by the 268 MB stream.
    const int gm = bm * TILE + m_w;
    const int gn = bn * TILE + n_w;
    float tq[4];
#pragma unroll
    for (int in = 0; in < 4; ++in) tq[in] = tsq[gn + in * 16 + r];
#pragma unroll
    for (int im = 0; im < 4; ++im) {
#pragma unroll
        for (int j = 0; j < 4; ++j) {
            const int i = gm + im * 16 + quad * 4 + j;
            const float sv = ssq[i];
            float* orow = out + (size_t)i * (size_t)Q + gn;
#pragma unroll
            for (int in = 0; in < 4; ++in)
                __builtin_nontemporal_store(sv + tq[in] + acc[im][in][j],
                                            &orow[in * 16 + r]);
        }
    }
}

// Correctness fallback if d_ws is too small for the bf16 copies.
__global__ void dist_fallback(const float* __restrict__ s, const float* __restrict__ t,
                              float* __restrict__ out, int N, int Q, int D) {
    __shared__ float ls[16][17], lt[16][17];
    const int tj = threadIdx.x, ti = threadIdx.y;
    const int i = blockIdx.y * 16 + ti, j = blockIdx.x * 16 + tj;
    float cross = 0.f, ssq = 0.f, tsq = 0.f;
    for (int k0 = 0; k0 < D; k0 += 16) {
        __syncthreads();
        ls[ti][tj] = s[(size_t)(blockIdx.y * 16 + ti) * D + k0 + tj];
        lt[ti][tj] = t[(size_t)(blockIdx.x * 16 + ti) * D + k0 + tj];
        __syncthreads();
#pragma unroll
        for (int kk = 0; kk < 16; ++kk) {
            float a = ls[ti][kk], b = lt[tj][kk];
            cross += a * b; ssq += a * a; tsq += b * b;
        }
    }
    out[(size_t)i * Q + j] = ssq + tsq - 2.f * cross;
}

extern "C" void kernel_launch(void* const* d_in, const int* in_sizes, int n_in,
                              void* d_out, int out_size, void* d_ws, size_t ws_size,
                              hipStream_t stream) {
    const float* s = (const float*)d_in[0];
    const float* t = (const float*)d_in[1];
    float* out = (float*)d_out;
    const int D = 512;
    const int N = in_sizes[0] / D;  // 8192
    const int Q = in_sizes[1] / D;  // 8192

    const size_t need = ((size_t)N + (size_t)Q) * D * sizeof(unsigned short)
                      + ((size_t)N + (size_t)Q) * sizeof(float);

    if (ws_size >= need && D == 512 && (N % TILE) == 0 && (Q % TILE) == 0) {
        unsigned short* sb = (unsigned short*)d_ws;
        unsigned short* tb = sb + (size_t)N * D;
        float* ssq = (float*)(tb + (size_t)Q * D);
        float* tsq = ssq + N;
        prep_kernel<<<(N + Q) / 4, 256, 0, stream>>>(s, t, sb, tb, ssq, tsq, N);
        const int blocks = (N / TILE) * (Q / TILE);
        dist_mfma<<<blocks, 256, 0, stream>>>(sb, tb, ssq, tsq, out, N, Q, D);
    } else {
        dim3 g(Q / 16, N / 16), b(16, 16);
        dist_fallback<<<g, b, 0, stream>>>(s, t, out, N, Q, D);
    }
}